// Round 10
// baseline (235.996 us; speedup 1.0000x reference)
//
#include <hip/hip_runtime.h>
#include <math.h>

#define NV   30000
#define DD   256
#define KK   32
#define NCLS 11
#define NT   469   // row tiles of 64 (k_heads, zhat layout)
#define NTZ  938   // row tiles of 32 (k_zout)

// output layout (floats)
#define OZ  0
#define OPB 7680000
#define OLG 7710000
#define OPL 8040000
#define OMB 8070000
#define OMS 8100000
#define OML 8130000
#define OOF 8160000
#define ORG 8190000

typedef __bf16 bf16x8 __attribute__((ext_vector_type(8)));
typedef float  f32x4  __attribute__((ext_vector_type(4)));

__device__ __forceinline__ unsigned short f2b(float f) {
    unsigned u = __float_as_uint(f);
    u += 0x7fffu + ((u >> 16) & 1u);
    return (unsigned short)(u >> 16);
}

// tanh-form gelu: x * sigmoid(x*(c0 + c1*x^2)); |err| ~3e-4 << bf16 quantization
__device__ __forceinline__ float gelu_f(float x) {
    float x2 = x * x;
    float m = x * __builtin_fmaf(-0.0713548163f, x2, -1.5957691216f);
    float e = __expf(m);
    return x * __builtin_amdgcn_rcpf(1.0f + e);
}

__device__ __forceinline__ int swz(int row) { return (row + (row >> 3)) & 7; }
__device__ __forceinline__ int lidx(int row, int col) {
    return row * 256 + ((((col) >> 3) ^ swz(row)) << 3) + (col & 7);
}
__device__ __forceinline__ int physchunk(int ck, int row) {
    return (ck & ~7) | ((ck & 7) ^ swz(row));
}
// proj-partials bank swizzle: column n XOR'd with k-slice bits (o>>2 == lq).
// Banks: 4-way (all lq same bank) -> 2-way pairs (free). Bijective on n (6 bits).
__device__ __forceinline__ int pswz(int o, int n) { return n ^ (((o >> 2) & 3) << 4); }

// ------ merged prep: y==0 projT(f32 dot, transposed), y=1..3 weight prep, y==4 masks ------
struct WP {
    const float *W1, *ng, *nb, *b1, *W2, *Wh;
    unsigned short *W1e, *W2b, *Whb;
    float *b1e, *swh;
    int nc;
};

__global__ void k_prep(const float* __restrict__ et, const float* __restrict__ Wp,
                       const float* __restrict__ bp, unsigned short* __restrict__ projT,
                       const float* __restrict__ vf, const int* __restrict__ vt,
                       float* __restrict__ out,
                       WP wa, WP wb, WP wc) {
    __shared__ float es[DD];
    __shared__ float red[4], red2[4];
    if (blockIdx.y == 0) {
        int r = blockIdx.x, c = threadIdx.x;
        es[c] = et[r * DD + c];
        __syncthreads();
        const float4* w4 = (const float4*)(Wp + c * DD);
        // 4 independent accumulators: break the serial FMA dependency chain
        float a0 = 0.f, a1 = 0.f, a2 = 0.f, a3 = 0.f;
#pragma unroll 16
        for (int d = 0; d < DD / 4; ++d) {
            float4 w = w4[d];
            a0 += es[4 * d] * w.x;
            a1 += es[4 * d + 1] * w.y;
            a2 += es[4 * d + 2] * w.z;
            a3 += es[4 * d + 3] * w.w;
        }
        float acc = bp[c] + ((a0 + a1) + (a2 + a3));
        projT[c * DD + r] = f2b(acc);   // transposed: [d][token]
        return;
    }
    if (blockIdx.y == 4) {
        int n = blockIdx.x * 256 + threadIdx.x;
        if (n < NV) {
            float lb = vf[n * 23 + 21], ub = vf[n * 23 + 22];
            int t = vt[n];
            bool is_int = (t == 2);
            bool finite = (fabsf(lb) < 1e18f) && (fabsf(ub) < 1e18f);
            bool small_ = is_int && finite && (ub - lb <= 10.0f);
            float off = floorf(lb);
            float rngf = ceilf(ub) - off + 1.0f;
            rngf = fminf(fmaxf(rngf, 1.0f), (float)NCLS);
            out[OMB + n] = (t == 1) ? 1.0f : 0.0f;
            out[OMS + n] = small_ ? 1.0f : 0.0f;
            out[OML + n] = (is_int && !small_) ? 1.0f : 0.0f;
            out[OOF + n] = off;
            out[ORG + n] = (float)((int)rngf);
        }
        return;
    }
    WP wp = (blockIdx.y == 1) ? wa : ((blockIdx.y == 2) ? wb : wc);
    int j = blockIdx.x, d = threadIdx.x;
    float v1 = wp.W1[j * DD + d];
    wp.W1e[j * DD + d] = f2b(v1 * wp.ng[d]);
    wp.W2b[j * DD + d] = f2b(wp.W2[j * DD + d]);
    float p2 = 0.f;
    if (j < 16) {
        p2 = (j < wp.nc) ? wp.Wh[j * DD + d] : 0.f;
        wp.Whb[j * DD + d] = f2b(p2);
    }
    float p = v1 * wp.nb[d];
#pragma unroll
    for (int m = 1; m < 64; m <<= 1) { p += __shfl_xor(p, m); p2 += __shfl_xor(p2, m); }
    if ((d & 63) == 0) { red[d >> 6] = p; red2[d >> 6] = p2; }
    __syncthreads();
    if (d == 0) {
        wp.b1e[j] = wp.b1[j] + red[0] + red[1] + red[2] + red[3];
        if (j < 16) wp.swh[j] = red2[0] + red2[1] + red2[2] + red2[3];
    }
}

// ---- MFMA k_zout: 32-row tiles (938 blocks, 3.7/CU) ----
// vb SORTED -> live K-window [vb[n0], vb[n0+31]] only (bit-identical: skipped
// chunks are all-zero A). Swizzle matches k_heads' 64-row tiles:
// swz(r + 32*half) = (swz(r) + 4*half) & 7.
__global__ __launch_bounds__(512)
void k_zout(const unsigned short* __restrict__ projT, const int* __restrict__ vb,
            const float* __restrict__ aw, const float* __restrict__ z0,
            const float* __restrict__ g, const float* __restrict__ b,
            const unsigned short* __restrict__ Whb, const float* __restrict__ swh,
            float* __restrict__ out, unsigned short* __restrict__ zhat,
            float* __restrict__ zwhT) {
    __shared__ unsigned short Al[32 * 256];   // 16 KB
    __shared__ float sqs[32 * 8], sqq[32 * 8];
    __shared__ float mvm[32], mvr[32], sig[32];
    __shared__ float gs[DD], bs[DD];
    __shared__ float swhs[48];
    int tid = threadIdx.x;
    int lane = tid & 63, wv = tid >> 6;
    int l15 = lane & 15, lq = lane >> 4;
    int n0 = blockIdx.x * 32;
    int sadd = (blockIdx.x & 1) << 2;   // 64-row-consistent swizzle offset

    int bmin = vb[n0];
    int bmax = vb[(n0 + 31 < NV) ? (n0 + 31) : (NV - 1)];

    if (tid < 256) gs[tid] = g[tid];
    else           bs[tid - 256] = b[tid - 256];
    if (tid < 48) swhs[tid] = swh[tid];
    {
        uint4 z4 = make_uint4(0, 0, 0, 0);
        uint4* dst = (uint4*)Al;
        dst[tid] = z4;
        dst[tid + 512] = z4;
    }
    __syncthreads();
    // scatter aw (bf16) into Al at col vb*32 (256 threads: 8/row)
    if (tid < 256) {
        int r = tid >> 3, sub = tid & 7;
        int n = n0 + r;
        if (n < NV) {
            int bb = vb[n];
            float4 a4 = *(const float4*)(aw + (size_t)n * KK + sub * 4);
            int j0 = bb * 32 + sub * 4;
            int ck = j0 >> 3;
            int chunk = (ck & ~7) | ((ck & 7) ^ ((swz(r) + sadd) & 7));
            int phys = r * 256 + (chunk << 3) + (j0 & 7);
            ushort4 u;
            u.x = f2b(a4.x); u.y = f2b(a4.y); u.z = f2b(a4.z); u.w = f2b(a4.w);
            *(ushort4*)(Al + phys) = u;
        }
    }
    __syncthreads();

    int nb0 = wv * 32;   // this wave's 32 d-columns
    f32x4 acc[2][2];
#pragma unroll
    for (int mt = 0; mt < 2; ++mt)
#pragma unroll
        for (int nt = 0; nt < 2; ++nt) acc[mt][nt] = f32x4{0.f, 0.f, 0.f, 0.f};

    // GEMM over live K-window only
    {
        const unsigned short* Bb = projT + (size_t)(nb0 + l15) * DD + lq * 8;
        for (int ks = bmin; ks <= bmax; ++ks) {
            bf16x8 bfr[2];
#pragma unroll
            for (int nt = 0; nt < 2; ++nt)
                bfr[nt] = *(const bf16x8*)(Bb + nt * 16 * DD + ks * 32);
            int ck = ks * 4 + lq;
#pragma unroll
            for (int mt = 0; mt < 2; ++mt) {
                int row = mt * 16 + l15;
                int chunk = (ck & ~7) | ((ck & 7) ^ ((swz(row) + sadd) & 7));
                bf16x8 afr = *(const bf16x8*)(Al + row * 256 + (chunk << 3));
#pragma unroll
                for (int nt = 0; nt < 2; ++nt)
                    acc[mt][nt] = __builtin_amdgcn_mfma_f32_16x16x32_bf16(afr, bfr[nt], acc[mt][nt], 0, 0, 0);
            }
        }
    }
    // add z0, LN1 partials
#pragma unroll
    for (int mt = 0; mt < 2; ++mt)
#pragma unroll
        for (int nt = 0; nt < 2; ++nt) {
            int col = nb0 + nt * 16 + l15;
#pragma unroll
            for (int r = 0; r < 4; ++r) {
                int n = n0 + mt * 16 + lq * 4 + r;
                float zv = (n < NV) ? z0[(size_t)n * DD + col] : 0.f;
                acc[mt][nt][r] += zv;
            }
        }
#pragma unroll
    for (int mt = 0; mt < 2; ++mt)
#pragma unroll
        for (int r = 0; r < 4; ++r) {
            float s = acc[mt][0][r] + acc[mt][1][r];
            float q = acc[mt][0][r] * acc[mt][0][r] + acc[mt][1][r] * acc[mt][1][r];
#pragma unroll
            for (int m = 1; m < 16; m <<= 1) { s += __shfl_xor(s, m); q += __shfl_xor(q, m); }
            if (l15 == 0) { int row = mt * 16 + lq * 4 + r; sqs[row * 8 + wv] = s; sqq[row * 8 + wv] = q; }
        }
    __syncthreads();
    if (tid < 32) {
        float s = 0.f, q = 0.f;
#pragma unroll
        for (int w = 0; w < 8; ++w) { s += sqs[tid * 8 + w]; q += sqq[tid * 8 + w]; }
        float mean = s * (1.f / DD);
        float var  = q * (1.f / DD) - mean * mean;
        mvm[tid] = mean; mvr[tid] = rsqrtf(var + 1e-5f);
    }
    __syncthreads();
    // z (in place into acc), write zout, LN2 partials
#pragma unroll
    for (int mt = 0; mt < 2; ++mt)
#pragma unroll
        for (int nt = 0; nt < 2; ++nt) {
            int col = nb0 + nt * 16 + l15;
#pragma unroll
            for (int r = 0; r < 4; ++r) {
                int row = mt * 16 + lq * 4 + r;
                float z = (acc[mt][nt][r] - mvm[row]) * mvr[row] * gs[col] + bs[col];
                acc[mt][nt][r] = z;
                int n = n0 + row;
                if (n < NV) out[OZ + (size_t)n * DD + col] = z;
            }
        }
#pragma unroll
    for (int mt = 0; mt < 2; ++mt)
#pragma unroll
        for (int r = 0; r < 4; ++r) {
            float s = acc[mt][0][r] + acc[mt][1][r];
            float q = acc[mt][0][r] * acc[mt][0][r] + acc[mt][1][r] * acc[mt][1][r];
#pragma unroll
            for (int m = 1; m < 16; m <<= 1) { s += __shfl_xor(s, m); q += __shfl_xor(q, m); }
            if (l15 == 0) { int row = mt * 16 + lq * 4 + r; sqs[row * 8 + wv] = s; sqq[row * 8 + wv] = q; }
        }
    __syncthreads();
    if (tid < 32) {
        float s = 0.f, q = 0.f;
#pragma unroll
        for (int w = 0; w < 8; ++w) { s += sqs[tid * 8 + w]; q += sqq[tid * 8 + w]; }
        float m2 = s * (1.f / DD);
        float v2 = q * (1.f / DD) - m2 * m2;
        float r2 = rsqrtf(v2 + 1e-5f);
        mvm[tid] = m2; mvr[tid] = r2; sig[tid] = (v2 + 1e-5f) * r2;
    }
    __syncthreads();
    // zhat (bf16) into Al (overwrite aw scatter)
#pragma unroll
    for (int mt = 0; mt < 2; ++mt)
#pragma unroll
        for (int nt = 0; nt < 2; ++nt) {
            int col = nb0 + nt * 16 + l15;
#pragma unroll
            for (int r = 0; r < 4; ++r) {
                int row = mt * 16 + lq * 4 + r;
                int idx = row * 256 + ((((col) >> 3) ^ ((swz(row) + sadd) & 7)) << 3) + (col & 7);
                Al[idx] = f2b((acc[mt][nt][r] - mvm[row]) * mvr[row]);
            }
        }
    __syncthreads();
    // zwh GEMM on waves 0..1: D[o(48)][n(16 per wave)]
    if (wv < 2) {
        f32x4 ac2[3];
#pragma unroll
        for (int mf = 0; mf < 3; ++mf) ac2[mf] = f32x4{0.f, 0.f, 0.f, 0.f};
        const unsigned short* Ab = Whb + (size_t)l15 * DD + lq * 8;
        int rowb = wv * 16 + l15;
        int sw = (swz(rowb) + sadd) & 7;
#pragma unroll
        for (int ks = 0; ks < 8; ++ks) {
            int ck = ks * 4 + lq;
            int chunk = (ck & ~7) | ((ck & 7) ^ sw);
            bf16x8 bb2 = *(const bf16x8*)(Al + rowb * 256 + (chunk << 3));
#pragma unroll
            for (int mf = 0; mf < 3; ++mf) {
                bf16x8 aa2 = *(const bf16x8*)(Ab + (size_t)mf * 16 * DD + ks * 32);
                ac2[mf] = __builtin_amdgcn_mfma_f32_16x16x32_bf16(aa2, bb2, ac2[mf], 0, 0, 0);
            }
        }
        int nl = wv * 16 + l15;
        float sg = sig[nl], mu = mvm[nl];
        int t64 = blockIdx.x >> 1, half = blockIdx.x & 1;
#pragma unroll
        for (int mf = 0; mf < 3; ++mf)
#pragma unroll
            for (int r = 0; r < 4; ++r) {
                int o = mf * 16 + lq * 4 + r;
                zwhT[(size_t)t64 * 3072 + o * 64 + half * 32 + nl] = sg * ac2[mf][r] + mu * swhs[o];
            }
    }
    // copy zhat half-tile out (pre-swizzled, 16 KB)
    {
        uint4* dstg = (uint4*)(zhat + (size_t)n0 * 256);
        const uint4* srcl = (const uint4*)Al;
        dstg[tid] = srcl[tid];
        dstg[tid + 512] = srcl[tid + 512];
    }
}

// ---------------- per-head MLP kernel: R8 structure + pswz partials ----------------
struct HeadP {
    const unsigned short *W1e, *W2b, *Whb;
    const float *b1e, *b2, *bh;
    int nc;
};

__global__ __launch_bounds__(512, 4)
void k_heads(const unsigned short* __restrict__ zhat, const float* __restrict__ zwhT,
             const float* __restrict__ ranges,
             HeadP h0, HeadP h1p, HeadP h2p,
             float* __restrict__ opb, float* __restrict__ olg, float* __restrict__ opl) {
    __shared__ unsigned short hl1[64 * 256];  // zhat -> h
    __shared__ unsigned short hl2[64 * 256];  // h1 -> f32 partials
    __shared__ float b1s[DD], b2s[DD];
    __shared__ float zws[16 * 64];
    __shared__ float rgs[64];
    __shared__ float bhs[16];

    int head = blockIdx.x / NT;
    int tile = blockIdx.x % NT;
    HeadP hp = (head == 0) ? h0 : ((head == 1) ? h1p : h2p);
    int nc = hp.nc;
    int n0 = tile * 64;
    int tid = threadIdx.x, lane = tid & 63, wv = tid >> 6;
    int l15 = lane & 15, lq = lane >> 4;
    int M0 = wv * 32;   // this wave's 32 feature rows

    {
        const uint4* src = (const uint4*)(zhat + (size_t)n0 * 256);
        uint4* dst = (uint4*)hl1;
#pragma unroll
        for (int j = 0; j < 4; ++j) dst[tid + j * 512] = src[tid + j * 512];
    }
    if (tid < 256) b1s[tid] = hp.b1e[tid];
    else           b2s[tid - 256] = hp.b2[tid - 256];
    ((float2*)zws)[tid] = ((const float2*)(zwhT + (size_t)(tile * 3 + head) * 1024))[tid];
    if (tid < 64) { int n = n0 + tid; rgs[tid] = (n < NV) ? ranges[n] : 0.f; }
    else if (tid < 80) { int o = tid - 64; bhs[o] = (o < nc) ? hp.bh[o] : 0.f; }
    __syncthreads();

    const unsigned short* Ab1 = hp.W1e + (size_t)(M0 + l15) * DD + lq * 8;
    const unsigned short* Ab2 = hp.W2b + (size_t)(M0 + l15) * DD + lq * 8;

    f32x4 acc[2][4];
#pragma unroll
    for (int mt = 0; mt < 2; ++mt)
#pragma unroll
        for (int nt = 0; nt < 4; ++nt) acc[mt][nt] = f32x4{0.f, 0.f, 0.f, 0.f};

    bf16x8 afr[3][2];   // depth-2 prefetch ring (L2 latency ~200cy > 1-ks cover)
#pragma unroll
    for (int mt = 0; mt < 2; ++mt) {
        afr[0][mt] = *(const bf16x8*)(Ab1 + mt * 16 * DD);
        afr[1][mt] = *(const bf16x8*)(Ab1 + mt * 16 * DD + 32);
    }

    // ---- GEMM1-T: D1[j][n], a = W1e rows (ring), b = zhat rows (LDS) ----
#pragma unroll
    for (int ks = 0; ks < 8; ++ks) {
        int cur = ks % 3;
        if (ks < 6) {
#pragma unroll
            for (int mt = 0; mt < 2; ++mt)
                afr[(ks + 2) % 3][mt] = *(const bf16x8*)(Ab1 + mt * 16 * DD + (ks + 2) * 32);
        }
        int ck = ks * 4 + lq;
        bf16x8 bfr[4];
#pragma unroll
        for (int nt = 0; nt < 4; ++nt) {
            int row = nt * 16 + l15;
            bfr[nt] = *(const bf16x8*)(hl1 + row * 256 + (physchunk(ck, row) << 3));
        }
#pragma unroll
        for (int nt = 0; nt < 4; ++nt)
#pragma unroll
            for (int mt = 0; mt < 2; ++mt)
                acc[mt][nt] = __builtin_amdgcn_mfma_f32_16x16x32_bf16(afr[cur][mt], bfr[nt], acc[mt][nt], 0, 0, 0);
    }

    // prefetch GEMM2's first two ring slots NOW: their L2 latency hides under
    // epilogue-1 VALU + the barrier drain (same registers, no extra pressure)
#pragma unroll
    for (int mt = 0; mt < 2; ++mt) {
        afr[0][mt] = *(const bf16x8*)(Ab2 + mt * 16 * DD);
        afr[1][mt] = *(const bf16x8*)(Ab2 + mt * 16 * DD + 32);
    }

    // epilogue 1 -> hl2 (different buffer; no barrier needed before writes)
#pragma unroll
    for (int mt = 0; mt < 2; ++mt) {
        int jb = M0 + mt * 16 + lq * 4;
        float4 bias = *(const float4*)(b1s + jb);
        int chunk = jb >> 3;
#pragma unroll
        for (int nt = 0; nt < 4; ++nt) {
            int n = nt * 16 + l15;
            ushort4 u;
            u.x = f2b(gelu_f(acc[mt][nt][0] + bias.x));
            u.y = f2b(gelu_f(acc[mt][nt][1] + bias.y));
            u.z = f2b(gelu_f(acc[mt][nt][2] + bias.z));
            u.w = f2b(gelu_f(acc[mt][nt][3] + bias.w));
            *(ushort4*)(hl2 + n * 256 + (physchunk(chunk, n) << 3) + (jb & 7)) = u;
        }
    }
    __syncthreads();

    // ---- GEMM2-T: a = W2b rows (ring), b = h1 rows (hl2) ----
#pragma unroll
    for (int mt = 0; mt < 2; ++mt)
#pragma unroll
        for (int nt = 0; nt < 4; ++nt) acc[mt][nt] = f32x4{0.f, 0.f, 0.f, 0.f};
#pragma unroll
    for (int ks = 0; ks < 8; ++ks) {
        int cur = ks % 3;
        if (ks < 6) {
#pragma unroll
            for (int mt = 0; mt < 2; ++mt)
                afr[(ks + 2) % 3][mt] = *(const bf16x8*)(Ab2 + mt * 16 * DD + (ks + 2) * 32);
        }
        int ck = ks * 4 + lq;
        bf16x8 bfr[4];
#pragma unroll
        for (int nt = 0; nt < 4; ++nt) {
            int row = nt * 16 + l15;
            bfr[nt] = *(const bf16x8*)(hl2 + row * 256 + (physchunk(ck, row) << 3));
        }
#pragma unroll
        for (int nt = 0; nt < 4; ++nt)
#pragma unroll
            for (int mt = 0; mt < 2; ++mt)
                acc[mt][nt] = __builtin_amdgcn_mfma_f32_16x16x32_bf16(afr[cur][mt], bfr[nt], acc[mt][nt], 0, 0, 0);
    }

    // prefetch proj's A-fragment: hides under epilogue-2 + barrier
    bf16x8 apr = *(const bf16x8*)(hp.Whb + (size_t)l15 * DD + wv * 32 + lq * 8);

    // epilogue 2: gelu -> h into hl1 (zhat dead after GEMM1+barrier)
#pragma unroll
    for (int mt = 0; mt < 2; ++mt) {
        int jb = M0 + mt * 16 + lq * 4;
        float4 bias = *(const float4*)(b2s + jb);
        int chunk = jb >> 3;
#pragma unroll
        for (int nt = 0; nt < 4; ++nt) {
            int n = nt * 16 + l15;
            ushort4 u;
            u.x = f2b(gelu_f(acc[mt][nt][0] + bias.x));
            u.y = f2b(gelu_f(acc[mt][nt][1] + bias.y));
            u.z = f2b(gelu_f(acc[mt][nt][2] + bias.z));
            u.w = f2b(gelu_f(acc[mt][nt][3] + bias.w));
            *(ushort4*)(hl1 + n * 256 + (physchunk(chunk, n) << 3) + (jb & 7)) = u;
        }
    }
    __syncthreads();

    // ---- projection: split-k, wave wv handles k-slice [wv*32, wv*32+32) ----
    f32x4 ap[4];
#pragma unroll
    for (int nt = 0; nt < 4; ++nt) ap[nt] = f32x4{0.f, 0.f, 0.f, 0.f};
    {
        int ck = wv * 4 + lq;
#pragma unroll
        for (int nt = 0; nt < 4; ++nt) {
            int row = nt * 16 + l15;
            bf16x8 bfr = *(const bf16x8*)(hl1 + row * 256 + (physchunk(ck, row) << 3));
            ap[nt] = __builtin_amdgcn_mfma_f32_16x16x32_bf16(apr, bfr, ap[nt], 0, 0, 0);
        }
    }
    // partials into hl2 (f32), bank-swizzled: o=lq*4+r, col stored at pswz(o,n).
    // Old layout was 4-way conflicted (all lq -> bank (nt*16+l15)%32); pswz
    // splits lq-pairs -> 2-way (free).
    {
        float* pb = (float*)hl2;
#pragma unroll
        for (int nt = 0; nt < 4; ++nt)
#pragma unroll
            for (int r = 0; r < 4; ++r) {
                int o = lq * 4 + r;
                int n = nt * 16 + l15;
                pb[wv * 1024 + o * 64 + pswz(o, n)] = ap[nt][r];
            }
    }
    __syncthreads();

    // combine + store
    const float* pb = (const float*)hl2;
    for (int idx = tid; idx < 64 * nc; idx += 512) {
        int o = idx >> 6, n = idx & 63;
        float val = bhs[o] + zws[o * 64 + n];
        int nsw = pswz(o, n);
#pragma unroll
        for (int w = 0; w < 8; ++w) val += pb[w * 1024 + o * 64 + nsw];
        int ng = n0 + n;
        if (ng < NV) {
            if (head == 0)      opb[ng] = __builtin_amdgcn_rcpf(1.f + __expf(-val));
            else if (head == 2) opl[ng] = val;
            else {
                int rng = (int)rgs[n];
                olg[(size_t)ng * NCLS + o] = (o < rng) ? val : -1e9f;
            }
        }
    }
}

extern "C" void kernel_launch(void* const* d_in, const int* in_sizes, int n_in,
                              void* d_out, int out_size, void* d_ws, size_t ws_size,
                              hipStream_t stream) {
    const float* et = (const float*)d_in[0];
    const int*   vb = (const int*)d_in[1];
    const float* aw = (const float*)d_in[2];
    const int*   vt = (const int*)d_in[3];
    const float* z0 = (const float*)d_in[4];
    const float* vf = (const float*)d_in[5];
    const float* Wp = (const float*)d_in[6];
    const float* bp = (const float*)d_in[7];
    const float* fg = (const float*)d_in[8];
    const float* fb = (const float*)d_in[9];
    float* out = (float*)d_out;

    char* ws = (char*)d_ws;
    unsigned short* projT = (unsigned short*)ws;              // 131072 B
    float* b1e           = (float*)(ws + 131072);             // 3072 (+pad)
    unsigned short* W1e  = (unsigned short*)(ws + 134144);    // 393216
    unsigned short* W2b  = (unsigned short*)(ws + 527360);    // 393216
    unsigned short* Whb  = (unsigned short*)(ws + 920576);    // 24576 (48 rows x 256)
    float* swh           = (float*)(ws + 945152);             // 192 (+pad)
    float* zwhT          = (float*)(ws + 945408);             // 469*3072*4 = 5763072
    unsigned short* zhat = (unsigned short*)(ws + 6708480);   // 469*64*512 = 15368192 -> ~22.1 MB

    WP wps[3];
    for (int h = 0; h < 3; ++h) {
        wps[h].W1 = (const float*)d_in[12 + 8 * h];
        wps[h].ng = (const float*)d_in[10 + 8 * h];
        wps[h].nb = (const float*)d_in[11 + 8 * h];
        wps[h].b1 = (const float*)d_in[13 + 8 * h];
        wps[h].W2 = (const float*)d_in[14 + 8 * h];
        wps[h].Wh = (const float*)d_in[16 + 8 * h];
        wps[h].W1e = W1e + h * 65536;
        wps[h].W2b = W2b + h * 65536;
        wps[h].Whb = Whb + h * 4096;
        wps[h].b1e = b1e + h * 256;
        wps[h].swh = swh + h * 16;
        wps[h].nc  = (h == 1) ? NCLS : 1;
    }
    k_prep<<<dim3(256, 5), 256, 0, stream>>>(et, Wp, bp, projT, vf, vt, out,
                                             wps[0], wps[1], wps[2]);

    k_zout<<<NTZ, 512, 0, stream>>>(projT, vb, aw, z0, fg, fb, Whb, swh,
                                    out, zhat, zwhT);

    HeadP hps[3];
    for (int h = 0; h < 3; ++h) {
        hps[h].W1e = W1e + h * 65536;
        hps[h].W2b = W2b + h * 65536;
        hps[h].Whb = Whb + h * 4096;
        hps[h].b1e = b1e + h * 256;
        hps[h].b2  = (const float*)d_in[15 + 8 * h];
        hps[h].bh  = (const float*)d_in[17 + 8 * h];
        hps[h].nc  = (h == 1) ? NCLS : 1;
    }
    k_heads<<<3 * NT, 512, 0, stream>>>(zhat, zwhT, out + ORG,
                                        hps[0], hps[1], hps[2],
                                        out + OPB, out + OLG, out + OPL);
}

// Round 11
// 232.519 us; speedup vs baseline: 1.0150x; 1.0150x over previous
//
#include <hip/hip_runtime.h>
#include <math.h>

#define NV   30000
#define DD   256
#define KK   32
#define NCLS 11
#define NT   469   // row tiles of 64 (k_heads, zhat layout)
#define NTZ  938   // row tiles of 32 (k_zout)
#define ZFS  260   // Zf row stride (floats): +4 pad kills store conflicts

// output layout (floats)
#define OZ  0
#define OPB 7680000
#define OLG 7710000
#define OPL 8040000
#define OMB 8070000
#define OMS 8100000
#define OML 8130000
#define OOF 8160000
#define ORG 8190000

typedef __bf16 bf16x8 __attribute__((ext_vector_type(8)));
typedef float  f32x4  __attribute__((ext_vector_type(4)));

__device__ __forceinline__ unsigned short f2b(float f) {
    unsigned u = __float_as_uint(f);
    u += 0x7fffu + ((u >> 16) & 1u);
    return (unsigned short)(u >> 16);
}

// tanh-form gelu: x * sigmoid(x*(c0 + c1*x^2)); |err| ~3e-4 << bf16 quantization
__device__ __forceinline__ float gelu_f(float x) {
    float x2 = x * x;
    float m = x * __builtin_fmaf(-0.0713548163f, x2, -1.5957691216f);
    float e = __expf(m);
    return x * __builtin_amdgcn_rcpf(1.0f + e);
}

__device__ __forceinline__ int swz(int row) { return (row + (row >> 3)) & 7; }
__device__ __forceinline__ int physchunk(int ck, int row) {
    return (ck & ~7) | ((ck & 7) ^ swz(row));
}
// proj-partials bank swizzle (k_heads): column n XOR'd with k-slice bits.
__device__ __forceinline__ int pswz(int o, int n) { return n ^ (((o >> 2) & 3) << 4); }

// ------ merged prep: y==0 projT(f32 dot, transposed), y=1..3 weight prep, y==4 masks ------
struct WP {
    const float *W1, *ng, *nb, *b1, *W2, *Wh;
    unsigned short *W1e, *W2b, *Whb;
    float *b1e, *swh;
    int nc;
};

__global__ void k_prep(const float* __restrict__ et, const float* __restrict__ Wp,
                       const float* __restrict__ bp, unsigned short* __restrict__ projT,
                       const float* __restrict__ vf, const int* __restrict__ vt,
                       float* __restrict__ out,
                       WP wa, WP wb, WP wc) {
    __shared__ float es[DD];
    __shared__ float red[4], red2[4];
    if (blockIdx.y == 0) {
        int r = blockIdx.x, c = threadIdx.x;
        es[c] = et[r * DD + c];
        __syncthreads();
        const float4* w4 = (const float4*)(Wp + c * DD);
        // 4 independent accumulators: break the serial FMA dependency chain
        float a0 = 0.f, a1 = 0.f, a2 = 0.f, a3 = 0.f;
#pragma unroll 16
        for (int d = 0; d < DD / 4; ++d) {
            float4 w = w4[d];
            a0 += es[4 * d] * w.x;
            a1 += es[4 * d + 1] * w.y;
            a2 += es[4 * d + 2] * w.z;
            a3 += es[4 * d + 3] * w.w;
        }
        float acc = bp[c] + ((a0 + a1) + (a2 + a3));
        projT[c * DD + r] = f2b(acc);   // transposed: [d][token]
        return;
    }
    if (blockIdx.y == 4) {
        int n = blockIdx.x * 256 + threadIdx.x;
        if (n < NV) {
            float lb = vf[n * 23 + 21], ub = vf[n * 23 + 22];
            int t = vt[n];
            bool is_int = (t == 2);
            bool finite = (fabsf(lb) < 1e18f) && (fabsf(ub) < 1e18f);
            bool small_ = is_int && finite && (ub - lb <= 10.0f);
            float off = floorf(lb);
            float rngf = ceilf(ub) - off + 1.0f;
            rngf = fminf(fmaxf(rngf, 1.0f), (float)NCLS);
            out[OMB + n] = (t == 1) ? 1.0f : 0.0f;
            out[OMS + n] = small_ ? 1.0f : 0.0f;
            out[OML + n] = (is_int && !small_) ? 1.0f : 0.0f;
            out[OOF + n] = off;
            out[ORG + n] = (float)((int)rngf);
        }
        return;
    }
    WP wp = (blockIdx.y == 1) ? wa : ((blockIdx.y == 2) ? wb : wc);
    int j = blockIdx.x, d = threadIdx.x;
    float v1 = wp.W1[j * DD + d];
    wp.W1e[j * DD + d] = f2b(v1 * wp.ng[d]);
    wp.W2b[j * DD + d] = f2b(wp.W2[j * DD + d]);
    float p2 = 0.f;
    if (j < 16) {
        p2 = (j < wp.nc) ? wp.Wh[j * DD + d] : 0.f;
        wp.Whb[j * DD + d] = f2b(p2);
    }
    float p = v1 * wp.nb[d];
#pragma unroll
    for (int m = 1; m < 64; m <<= 1) { p += __shfl_xor(p, m); p2 += __shfl_xor(p2, m); }
    if ((d & 63) == 0) { red[d >> 6] = p; red2[d >> 6] = p2; }
    __syncthreads();
    if (d == 0) {
        wp.b1e[j] = wp.b1[j] + red[0] + red[1] + red[2] + red[3];
        if (j < 16) wp.swh[j] = red2[0] + red2[1] + red2[2] + red2[3];
    }
}

// ---- MFMA k_zout: 32-row tiles; coalesced post-GEMM passes via Zf[32][260] ----
// vb SORTED -> live K-window only (bit-identical). Post-GEMM: fragments -> Zf,
// then 3 wave-per-row coalesced passes: z0-add+LN1, LN-apply+z-write+LN2,
// zhat pack (Al swizzled + direct global write). z0/z I/O is float4 (was 4B/lane).
__global__ __launch_bounds__(512)
void k_zout(const unsigned short* __restrict__ projT, const int* __restrict__ vb,
            const float* __restrict__ aw, const float* __restrict__ z0,
            const float* __restrict__ g, const float* __restrict__ b,
            const unsigned short* __restrict__ Whb, const float* __restrict__ swh,
            float* __restrict__ out, unsigned short* __restrict__ zhat,
            float* __restrict__ zwhT) {
    __shared__ unsigned short Al[32 * 256];   // 16 KB: aw scatter -> zhat
    __shared__ float Zf[32 * ZFS];            // 33.3 KB f32 staging
    __shared__ float sA[32], qA[32];
    __shared__ float mvm[32], mvr[32], sig[32];
    __shared__ float gs[DD], bs[DD];
    __shared__ float swhs[48];
    int tid = threadIdx.x;
    int lane = tid & 63, wv = tid >> 6;
    int l15 = lane & 15, lq = lane >> 4;
    int n0 = blockIdx.x * 32;
    int sadd = (blockIdx.x & 1) << 2;   // 64-row-consistent swizzle offset

    int bmin = vb[n0];
    int bmax = vb[(n0 + 31 < NV) ? (n0 + 31) : (NV - 1)];

    if (tid < 256) gs[tid] = g[tid];
    else           bs[tid - 256] = b[tid - 256];
    if (tid < 48) swhs[tid] = swh[tid];
    {
        uint4 z4 = make_uint4(0, 0, 0, 0);
        uint4* dst = (uint4*)Al;
        dst[tid] = z4;
        dst[tid + 512] = z4;
    }
    __syncthreads();
    // scatter aw (bf16) into Al at col vb*32 (256 threads: 8/row)
    if (tid < 256) {
        int r = tid >> 3, sub = tid & 7;
        int n = n0 + r;
        if (n < NV) {
            int bb = vb[n];
            float4 a4 = *(const float4*)(aw + (size_t)n * KK + sub * 4);
            int j0 = bb * 32 + sub * 4;
            int ck = j0 >> 3;
            int chunk = (ck & ~7) | ((ck & 7) ^ ((swz(r) + sadd) & 7));
            int phys = r * 256 + (chunk << 3) + (j0 & 7);
            ushort4 u;
            u.x = f2b(a4.x); u.y = f2b(a4.y); u.z = f2b(a4.z); u.w = f2b(a4.w);
            *(ushort4*)(Al + phys) = u;
        }
    }
    __syncthreads();

    int nb0 = wv * 32;   // this wave's 32 d-columns
    f32x4 acc[2][2];
#pragma unroll
    for (int mt = 0; mt < 2; ++mt)
#pragma unroll
        for (int nt = 0; nt < 2; ++nt) acc[mt][nt] = f32x4{0.f, 0.f, 0.f, 0.f};

    // GEMM over live K-window only
    {
        const unsigned short* Bb = projT + (size_t)(nb0 + l15) * DD + lq * 8;
        for (int ks = bmin; ks <= bmax; ++ks) {
            bf16x8 bfr[2];
#pragma unroll
            for (int nt = 0; nt < 2; ++nt)
                bfr[nt] = *(const bf16x8*)(Bb + nt * 16 * DD + ks * 32);
            int ck = ks * 4 + lq;
#pragma unroll
            for (int mt = 0; mt < 2; ++mt) {
                int row = mt * 16 + l15;
                int chunk = (ck & ~7) | ((ck & 7) ^ ((swz(row) + sadd) & 7));
                bf16x8 afr = *(const bf16x8*)(Al + row * 256 + (chunk << 3));
#pragma unroll
                for (int nt = 0; nt < 2; ++nt)
                    acc[mt][nt] = __builtin_amdgcn_mfma_f32_16x16x32_bf16(afr, bfr[nt], acc[mt][nt], 0, 0, 0);
            }
        }
    }
    // dump fragments to Zf[token][col] (2-way bank aliasing only: free)
#pragma unroll
    for (int mt = 0; mt < 2; ++mt)
#pragma unroll
        for (int nt = 0; nt < 2; ++nt) {
            int col = nb0 + nt * 16 + l15;
#pragma unroll
            for (int r = 0; r < 4; ++r) {
                int row = mt * 16 + lq * 4 + r;
                Zf[row * ZFS + col] = acc[mt][nt][r];
            }
        }
    __syncthreads();

    // pass 1: + z0 (float4 coalesced), LN1 row-sums (one wave = one token-row)
#pragma unroll
    for (int i = 0; i < 4; ++i) {
        int token = wv + i * 8;
        int n = n0 + token;
        float4 zv = make_float4(0.f, 0.f, 0.f, 0.f);
        if (n < NV) zv = *(const float4*)(z0 + (size_t)n * DD + lane * 4);
        float* zr = Zf + token * ZFS + lane * 4;
        float4 v = *(float4*)zr;
        v.x += zv.x; v.y += zv.y; v.z += zv.z; v.w += zv.w;
        *(float4*)zr = v;
        float s = (v.x + v.y) + (v.z + v.w);
        float q = v.x * v.x + v.y * v.y + v.z * v.z + v.w * v.w;
#pragma unroll
        for (int m = 1; m < 64; m <<= 1) { s += __shfl_xor(s, m); q += __shfl_xor(q, m); }
        if (lane == 0) { sA[token] = s; qA[token] = q; }
    }
    __syncthreads();
    if (tid < 32) {
        float mean = sA[tid] * (1.f / DD);
        float var  = qA[tid] * (1.f / DD) - mean * mean;
        mvm[tid] = mean; mvr[tid] = rsqrtf(var + 1e-5f);
    }
    __syncthreads();

    // pass 2: z = LN1(v); write out (float4); LN2 row-sums; keep z in Zf
#pragma unroll
    for (int i = 0; i < 4; ++i) {
        int token = wv + i * 8;
        int n = n0 + token;
        float* zr = Zf + token * ZFS + lane * 4;
        float4 v = *(float4*)zr;
        float m = mvm[token], rr = mvr[token];
        const float4 g4 = *(const float4*)(gs + lane * 4);
        const float4 b4 = *(const float4*)(bs + lane * 4);
        float4 z;
        z.x = (v.x - m) * rr * g4.x + b4.x;
        z.y = (v.y - m) * rr * g4.y + b4.y;
        z.z = (v.z - m) * rr * g4.z + b4.z;
        z.w = (v.w - m) * rr * g4.w + b4.w;
        if (n < NV) *(float4*)(out + OZ + (size_t)n * DD + lane * 4) = z;
        *(float4*)zr = z;
        float s = (z.x + z.y) + (z.z + z.w);
        float q = z.x * z.x + z.y * z.y + z.z * z.z + z.w * z.w;
#pragma unroll
        for (int m2_ = 1; m2_ < 64; m2_ <<= 1) { s += __shfl_xor(s, m2_); q += __shfl_xor(q, m2_); }
        if (lane == 0) { sA[token] = s; qA[token] = q; }
    }
    __syncthreads();
    if (tid < 32) {
        float m2 = sA[tid] * (1.f / DD);
        float v2 = qA[tid] * (1.f / DD) - m2 * m2;
        float r2 = rsqrtf(v2 + 1e-5f);
        mvm[tid] = m2; mvr[tid] = r2; sig[tid] = (v2 + 1e-5f) * r2;
    }
    __syncthreads();

    // pass 3: zhat (bf16) -> Al (swizzled) AND direct global zhat write
#pragma unroll
    for (int i = 0; i < 4; ++i) {
        int token = wv + i * 8;
        int c4 = lane * 4;
        const float* zr = Zf + token * ZFS + c4;
        float4 z = *(const float4*)zr;
        float m = mvm[token], rr = mvr[token];
        ushort4 u;
        u.x = f2b((z.x - m) * rr);
        u.y = f2b((z.y - m) * rr);
        u.z = f2b((z.z - m) * rr);
        u.w = f2b((z.w - m) * rr);
        int ck = c4 >> 3;
        int chunk = (ck & ~7) | ((ck & 7) ^ ((swz(token) + sadd) & 7));
        int off = (chunk << 3) + (c4 & 7);
        *(ushort4*)(Al + token * 256 + off) = u;
        *(ushort4*)(zhat + (size_t)(n0 + token) * 256 + off) = u;
    }
    __syncthreads();

    // zwh GEMM on waves 0..1: D[o(48)][n(16 per wave)]
    if (wv < 2) {
        f32x4 ac2[3];
#pragma unroll
        for (int mf = 0; mf < 3; ++mf) ac2[mf] = f32x4{0.f, 0.f, 0.f, 0.f};
        const unsigned short* Ab = Whb + (size_t)l15 * DD + lq * 8;
        int rowb = wv * 16 + l15;
        int sw = (swz(rowb) + sadd) & 7;
#pragma unroll
        for (int ks = 0; ks < 8; ++ks) {
            int ck = ks * 4 + lq;
            int chunk = (ck & ~7) | ((ck & 7) ^ sw);
            bf16x8 bb2 = *(const bf16x8*)(Al + rowb * 256 + (chunk << 3));
#pragma unroll
            for (int mf = 0; mf < 3; ++mf) {
                bf16x8 aa2 = *(const bf16x8*)(Ab + (size_t)mf * 16 * DD + ks * 32);
                ac2[mf] = __builtin_amdgcn_mfma_f32_16x16x32_bf16(aa2, bb2, ac2[mf], 0, 0, 0);
            }
        }
        int nl = wv * 16 + l15;
        float sg = sig[nl], mu = mvm[nl];
        int t64 = blockIdx.x >> 1, half = blockIdx.x & 1;
#pragma unroll
        for (int mf = 0; mf < 3; ++mf)
#pragma unroll
            for (int r = 0; r < 4; ++r) {
                int o = mf * 16 + lq * 4 + r;
                zwhT[(size_t)t64 * 3072 + o * 64 + half * 32 + nl] = sg * ac2[mf][r] + mu * swhs[o];
            }
    }
}

// ---------------- per-head MLP kernel: R8 structure + pswz partials ----------------
struct HeadP {
    const unsigned short *W1e, *W2b, *Whb;
    const float *b1e, *b2, *bh;
    int nc;
};

__global__ __launch_bounds__(512, 4)
void k_heads(const unsigned short* __restrict__ zhat, const float* __restrict__ zwhT,
             const float* __restrict__ ranges,
             HeadP h0, HeadP h1p, HeadP h2p,
             float* __restrict__ opb, float* __restrict__ olg, float* __restrict__ opl) {
    __shared__ unsigned short hl1[64 * 256];  // zhat -> h
    __shared__ unsigned short hl2[64 * 256];  // h1 -> f32 partials
    __shared__ float b1s[DD], b2s[DD];
    __shared__ float zws[16 * 64];
    __shared__ float rgs[64];
    __shared__ float bhs[16];

    int head = blockIdx.x / NT;
    int tile = blockIdx.x % NT;
    HeadP hp = (head == 0) ? h0 : ((head == 1) ? h1p : h2p);
    int nc = hp.nc;
    int n0 = tile * 64;
    int tid = threadIdx.x, lane = tid & 63, wv = tid >> 6;
    int l15 = lane & 15, lq = lane >> 4;
    int M0 = wv * 32;   // this wave's 32 feature rows

    {
        const uint4* src = (const uint4*)(zhat + (size_t)n0 * 256);
        uint4* dst = (uint4*)hl1;
#pragma unroll
        for (int j = 0; j < 4; ++j) dst[tid + j * 512] = src[tid + j * 512];
    }
    if (tid < 256) b1s[tid] = hp.b1e[tid];
    else           b2s[tid - 256] = hp.b2[tid - 256];
    ((float2*)zws)[tid] = ((const float2*)(zwhT + (size_t)(tile * 3 + head) * 1024))[tid];
    if (tid < 64) { int n = n0 + tid; rgs[tid] = (n < NV) ? ranges[n] : 0.f; }
    else if (tid < 80) { int o = tid - 64; bhs[o] = (o < nc) ? hp.bh[o] : 0.f; }
    __syncthreads();

    const unsigned short* Ab1 = hp.W1e + (size_t)(M0 + l15) * DD + lq * 8;
    const unsigned short* Ab2 = hp.W2b + (size_t)(M0 + l15) * DD + lq * 8;

    f32x4 acc[2][4];
#pragma unroll
    for (int mt = 0; mt < 2; ++mt)
#pragma unroll
        for (int nt = 0; nt < 4; ++nt) acc[mt][nt] = f32x4{0.f, 0.f, 0.f, 0.f};

    bf16x8 afr[3][2];   // depth-2 prefetch ring (L2 latency ~200cy > 1-ks cover)
#pragma unroll
    for (int mt = 0; mt < 2; ++mt) {
        afr[0][mt] = *(const bf16x8*)(Ab1 + mt * 16 * DD);
        afr[1][mt] = *(const bf16x8*)(Ab1 + mt * 16 * DD + 32);
    }

    // ---- GEMM1-T: D1[j][n], a = W1e rows (ring), b = zhat rows (LDS) ----
#pragma unroll
    for (int ks = 0; ks < 8; ++ks) {
        int cur = ks % 3;
        if (ks < 6) {
#pragma unroll
            for (int mt = 0; mt < 2; ++mt)
                afr[(ks + 2) % 3][mt] = *(const bf16x8*)(Ab1 + mt * 16 * DD + (ks + 2) * 32);
        }
        int ck = ks * 4 + lq;
        bf16x8 bfr[4];
#pragma unroll
        for (int nt = 0; nt < 4; ++nt) {
            int row = nt * 16 + l15;
            bfr[nt] = *(const bf16x8*)(hl1 + row * 256 + (physchunk(ck, row) << 3));
        }
#pragma unroll
        for (int nt = 0; nt < 4; ++nt)
#pragma unroll
            for (int mt = 0; mt < 2; ++mt)
                acc[mt][nt] = __builtin_amdgcn_mfma_f32_16x16x32_bf16(afr[cur][mt], bfr[nt], acc[mt][nt], 0, 0, 0);
    }

    // prefetch GEMM2's first two ring slots NOW: their L2 latency hides under
    // epilogue-1 VALU + the barrier drain (same registers, no extra pressure)
#pragma unroll
    for (int mt = 0; mt < 2; ++mt) {
        afr[0][mt] = *(const bf16x8*)(Ab2 + mt * 16 * DD);
        afr[1][mt] = *(const bf16x8*)(Ab2 + mt * 16 * DD + 32);
    }

    // epilogue 1 -> hl2 (different buffer; no barrier needed before writes)
#pragma unroll
    for (int mt = 0; mt < 2; ++mt) {
        int jb = M0 + mt * 16 + lq * 4;
        float4 bias = *(const float4*)(b1s + jb);
        int chunk = jb >> 3;
#pragma unroll
        for (int nt = 0; nt < 4; ++nt) {
            int n = nt * 16 + l15;
            ushort4 u;
            u.x = f2b(gelu_f(acc[mt][nt][0] + bias.x));
            u.y = f2b(gelu_f(acc[mt][nt][1] + bias.y));
            u.z = f2b(gelu_f(acc[mt][nt][2] + bias.z));
            u.w = f2b(gelu_f(acc[mt][nt][3] + bias.w));
            *(ushort4*)(hl2 + n * 256 + (physchunk(chunk, n) << 3) + (jb & 7)) = u;
        }
    }
    __syncthreads();

    // ---- GEMM2-T: a = W2b rows (ring), b = h1 rows (hl2) ----
#pragma unroll
    for (int mt = 0; mt < 2; ++mt)
#pragma unroll
        for (int nt = 0; nt < 4; ++nt) acc[mt][nt] = f32x4{0.f, 0.f, 0.f, 0.f};
#pragma unroll
    for (int ks = 0; ks < 8; ++ks) {
        int cur = ks % 3;
        if (ks < 6) {
#pragma unroll
            for (int mt = 0; mt < 2; ++mt)
                afr[(ks + 2) % 3][mt] = *(const bf16x8*)(Ab2 + mt * 16 * DD + (ks + 2) * 32);
        }
        int ck = ks * 4 + lq;
        bf16x8 bfr[4];
#pragma unroll
        for (int nt = 0; nt < 4; ++nt) {
            int row = nt * 16 + l15;
            bfr[nt] = *(const bf16x8*)(hl2 + row * 256 + (physchunk(ck, row) << 3));
        }
#pragma unroll
        for (int nt = 0; nt < 4; ++nt)
#pragma unroll
            for (int mt = 0; mt < 2; ++mt)
                acc[mt][nt] = __builtin_amdgcn_mfma_f32_16x16x32_bf16(afr[cur][mt], bfr[nt], acc[mt][nt], 0, 0, 0);
    }

    // prefetch proj's A-fragment: hides under epilogue-2 + barrier
    bf16x8 apr = *(const bf16x8*)(hp.Whb + (size_t)l15 * DD + wv * 32 + lq * 8);

    // epilogue 2: gelu -> h into hl1 (zhat dead after GEMM1+barrier)
#pragma unroll
    for (int mt = 0; mt < 2; ++mt) {
        int jb = M0 + mt * 16 + lq * 4;
        float4 bias = *(const float4*)(b2s + jb);
        int chunk = jb >> 3;
#pragma unroll
        for (int nt = 0; nt < 4; ++nt) {
            int n = nt * 16 + l15;
            ushort4 u;
            u.x = f2b(gelu_f(acc[mt][nt][0] + bias.x));
            u.y = f2b(gelu_f(acc[mt][nt][1] + bias.y));
            u.z = f2b(gelu_f(acc[mt][nt][2] + bias.z));
            u.w = f2b(gelu_f(acc[mt][nt][3] + bias.w));
            *(ushort4*)(hl1 + n * 256 + (physchunk(chunk, n) << 3) + (jb & 7)) = u;
        }
    }
    __syncthreads();

    // ---- projection: split-k, wave wv handles k-slice [wv*32, wv*32+32) ----
    f32x4 ap[4];
#pragma unroll
    for (int nt = 0; nt < 4; ++nt) ap[nt] = f32x4{0.f, 0.f, 0.f, 0.f};
    {
        int ck = wv * 4 + lq;
#pragma unroll
        for (int nt = 0; nt < 4; ++nt) {
            int row = nt * 16 + l15;
            bf16x8 bfr = *(const bf16x8*)(hl1 + row * 256 + (physchunk(ck, row) << 3));
            ap[nt] = __builtin_amdgcn_mfma_f32_16x16x32_bf16(apr, bfr, ap[nt], 0, 0, 0);
        }
    }
    // partials into hl2 (f32), bank-swizzled (pswz): 2-way = free
    {
        float* pb = (float*)hl2;
#pragma unroll
        for (int nt = 0; nt < 4; ++nt)
#pragma unroll
            for (int r = 0; r < 4; ++r) {
                int o = lq * 4 + r;
                int n = nt * 16 + l15;
                pb[wv * 1024 + o * 64 + pswz(o, n)] = ap[nt][r];
            }
    }
    __syncthreads();

    // combine + store
    const float* pb = (const float*)hl2;
    for (int idx = tid; idx < 64 * nc; idx += 512) {
        int o = idx >> 6, n = idx & 63;
        float val = bhs[o] + zws[o * 64 + n];
        int nsw = pswz(o, n);
#pragma unroll
        for (int w = 0; w < 8; ++w) val += pb[w * 1024 + o * 64 + nsw];
        int ng = n0 + n;
        if (ng < NV) {
            if (head == 0)      opb[ng] = __builtin_amdgcn_rcpf(1.f + __expf(-val));
            else if (head == 2) opl[ng] = val;
            else {
                int rng = (int)rgs[n];
                olg[(size_t)ng * NCLS + o] = (o < rng) ? val : -1e9f;
            }
        }
    }
}

extern "C" void kernel_launch(void* const* d_in, const int* in_sizes, int n_in,
                              void* d_out, int out_size, void* d_ws, size_t ws_size,
                              hipStream_t stream) {
    const float* et = (const float*)d_in[0];
    const int*   vb = (const int*)d_in[1];
    const float* aw = (const float*)d_in[2];
    const int*   vt = (const int*)d_in[3];
    const float* z0 = (const float*)d_in[4];
    const float* vf = (const float*)d_in[5];
    const float* Wp = (const float*)d_in[6];
    const float* bp = (const float*)d_in[7];
    const float* fg = (const float*)d_in[8];
    const float* fb = (const float*)d_in[9];
    float* out = (float*)d_out;

    char* ws = (char*)d_ws;
    unsigned short* projT = (unsigned short*)ws;              // 131072 B
    float* b1e           = (float*)(ws + 131072);             // 3072 (+pad)
    unsigned short* W1e  = (unsigned short*)(ws + 134144);    // 393216
    unsigned short* W2b  = (unsigned short*)(ws + 527360);    // 393216
    unsigned short* Whb  = (unsigned short*)(ws + 920576);    // 24576 (48 rows x 256)
    float* swh           = (float*)(ws + 945152);             // 192 (+pad)
    float* zwhT          = (float*)(ws + 945408);             // 469*3072*4 = 5763072
    unsigned short* zhat = (unsigned short*)(ws + 6708480);   // 469*64*512 = 15368192 -> ~22.1 MB

    WP wps[3];
    for (int h = 0; h < 3; ++h) {
        wps[h].W1 = (const float*)d_in[12 + 8 * h];
        wps[h].ng = (const float*)d_in[10 + 8 * h];
        wps[h].nb = (const float*)d_in[11 + 8 * h];
        wps[h].b1 = (const float*)d_in[13 + 8 * h];
        wps[h].W2 = (const float*)d_in[14 + 8 * h];
        wps[h].Wh = (const float*)d_in[16 + 8 * h];
        wps[h].W1e = W1e + h * 65536;
        wps[h].W2b = W2b + h * 65536;
        wps[h].Whb = Whb + h * 4096;
        wps[h].b1e = b1e + h * 256;
        wps[h].swh = swh + h * 16;
        wps[h].nc  = (h == 1) ? NCLS : 1;
    }
    k_prep<<<dim3(256, 5), 256, 0, stream>>>(et, Wp, bp, projT, vf, vt, out,
                                             wps[0], wps[1], wps[2]);

    k_zout<<<NTZ, 512, 0, stream>>>(projT, vb, aw, z0, fg, fb, Whb, swh,
                                    out, zhat, zwhT);

    HeadP hps[3];
    for (int h = 0; h < 3; ++h) {
        hps[h].W1e = W1e + h * 65536;
        hps[h].W2b = W2b + h * 65536;
        hps[h].Whb = Whb + h * 4096;
        hps[h].b1e = b1e + h * 256;
        hps[h].b2  = (const float*)d_in[15 + 8 * h];
        hps[h].bh  = (const float*)d_in[17 + 8 * h];
        hps[h].nc  = (h == 1) ? NCLS : 1;
    }
    k_heads<<<3 * NT, 512, 0, stream>>>(zhat, zwhT, out + ORG,
                                        hps[0], hps[1], hps[2],
                                        out + OPB, out + OLG, out + OPL);
}